// Round 6
// baseline (172.285 us; speedup 1.0000x reference)
//
#include <hip/hip_runtime.h>

typedef unsigned short u16;
typedef unsigned int u32;

typedef __bf16 bf16x8 __attribute__((ext_vector_type(8)));
typedef _Float16 f16x8 __attribute__((ext_vector_type(8)));
typedef float f32x4 __attribute__((ext_vector_type(4)));
typedef u32 u32x4 __attribute__((ext_vector_type(4)));

typedef __attribute__((address_space(1))) u32 as1_u32;
typedef __attribute__((address_space(3))) u32 as3_u32;

#define EKF 0.18033688011112042f  // 0.125 * log2(e), folded into Q at GEMM1

__device__ __forceinline__ u16 f2bf(float x) {
  u32 u = __float_as_uint(x);
  u = u + 0x7fffu + ((u >> 16) & 1u);   // RNE
  return (u16)(u >> 16);
}
__device__ __forceinline__ u32 pack2(float a, float b) {
  return (u32)f2bf(a) | ((u32)f2bf(b) << 16);
}
__device__ __forceinline__ u32 pkf16(float a, float b) {
  return __builtin_bit_cast(u32, __builtin_amdgcn_cvt_pkrtz(a, b));
}
__device__ __forceinline__ u16 f2h(float a) {
  return (u16)(pkf16(a, a) & 0xffffu);
}
__device__ __forceinline__ void gld_lds16(const u16* g, const u16* l) {
  __builtin_amdgcn_global_load_lds((const as1_u32*)g, (as3_u32*)l, 16, 0, 0);
}

// ---------------- fused prepass: x cast + both weight transposes ----------------
__global__ __launch_bounds__(256) void prepass_kernel(const float* __restrict__ x,
                                                      const float* __restrict__ w_qkv,
                                                      const float* __restrict__ w_out,
                                                      u16* __restrict__ xb,
                                                      u16* __restrict__ wqkvT,
                                                      u16* __restrict__ woutT) {
  __shared__ float tile[64][65];
  int bid = blockIdx.x;
  int t = threadIdx.x;
  if (bid < 4096) {
    int i = bid * 256 + t;
    float4 v = ((const float4*)x)[i];
    uint2 r;
    r.x = pack2(v.x, v.y);
    r.y = pack2(v.z, v.w);
    ((uint2*)xb)[i] = r;
    return;
  }
  const float* W;
  u16* WT;
  int K, N, bx, by;
  if (bid < 4096 + 768) {
    int b2 = bid - 4096;
    W = w_qkv; WT = wqkvT; K = 1024; N = 3072; bx = b2 & 15; by = b2 >> 4;
  } else {
    int b2 = bid - 4864;
    W = w_out; WT = woutT; K = 1024; N = 1024; bx = b2 & 15; by = b2 >> 4;
  }
  int k0 = bx * 64, n0 = by * 64;
  int r = t >> 4, c4 = (t & 15) * 4;
#pragma unroll
  for (int i = 0; i < 4; ++i) {
    int row = r + i * 16;
    float4 v = *(const float4*)&W[(size_t)(k0 + row) * N + n0 + c4];
    tile[row][c4 + 0] = v.x; tile[row][c4 + 1] = v.y;
    tile[row][c4 + 2] = v.z; tile[row][c4 + 3] = v.w;
  }
  __syncthreads();
#pragma unroll
  for (int i = 0; i < 4; ++i) {
    int n = r + i * 16;
    uint2 o;
    o.x = pack2(tile[c4 + 0][n], tile[c4 + 1][n]);
    o.y = pack2(tile[c4 + 2][n], tile[c4 + 3][n]);
    *(uint2*)&WT[(size_t)(n0 + n) * K + k0 + c4] = o;
  }
}

// ---------------- 256x256 8-phase QKV GEMM (unchanged) ----------------
__global__ __launch_bounds__(512, 2) void gemm_qkv256_kernel(const u16* __restrict__ A,
                                                             const u16* __restrict__ BT,
                                                             u16* __restrict__ QK,
                                                             u16* __restrict__ VT) {
  __shared__ __attribute__((aligned(16))) u16 smem[65536];  // 128 KiB -> 1 block/CU
  const int tid = threadIdx.x;
  const int wave = tid >> 6;
  const int lane = tid & 63;
  const int lr = lane & 15;
  const int kg = lane >> 4;
  const int l7 = lr & 7;
  const int wr = wave >> 2;   // 0..1 : M half
  const int wc = wave & 3;    // 0..3 : N quarter

  int b = blockIdx.x;
  int sw = (b & 7) * 24 + (b >> 3);
  const int bn = (sw % 12) * 256;
  const int bm = (sw / 12) * 256;

  const int srow = tid >> 3;
  const int scg = ((tid & 7) ^ (srow & 7)) * 8;  // swizzled source col (u16)
  const u16* pa = A + (size_t)(bm + srow) * 1024 + scg;
  const u16* pb = BT + (size_t)(bn + srow) * 1024 + scg;
  const u32 lw = (u32)wave * 512;

  f32x4 acc[8][4];
#pragma unroll
  for (int i = 0; i < 8; ++i)
#pragma unroll
    for (int j = 0; j < 4; ++j) {
      f32x4 z = {0.f, 0.f, 0.f, 0.f};
      acc[i][j] = z;
    }

  {
    u16* dA = (u16*)smem;
    u16* dB = (u16*)smem + 16384;
#pragma unroll
    for (int i = 0; i < 4; ++i) gld_lds16(pa + (size_t)(i * 64) * 1024, dA + lw + i * 4096);
#pragma unroll
    for (int i = 0; i < 4; ++i) gld_lds16(pb + (size_t)(i * 64) * 1024, dB + lw + i * 4096);
  }

  for (int t = 0; t < 16; ++t) {
    __syncthreads();
    const u16* bA = smem + (t & 1) * 32768;
    const u16* bB = bA + 16384;
    if (t + 1 < 16) {
      u16* dA = (u16*)smem + ((t + 1) & 1) * 32768;
      u16* dB = dA + 16384;
      const int k1 = (t + 1) * 64;
#pragma unroll
      for (int i = 0; i < 4; ++i) gld_lds16(pa + (size_t)(i * 64) * 1024 + k1, dA + lw + i * 4096);
#pragma unroll
      for (int i = 0; i < 4; ++i) gld_lds16(pb + (size_t)(i * 64) * 1024 + k1, dB + lw + i * 4096);
    }
    bf16x8 bfr[2][4];
#pragma unroll
    for (int kh = 0; kh < 2; ++kh)
#pragma unroll
      for (int ni = 0; ni < 4; ++ni)
        bfr[kh][ni] = *(const bf16x8*)(bB + (wc * 64 + ni * 16 + lr) * 64 +
                                       (((kh * 4 + kg) ^ l7) * 8));
#pragma unroll
    for (int ph = 0; ph < 4; ++ph) {
      const int mh = ph >> 1, kh = ph & 1;
      bf16x8 af[4];
#pragma unroll
      for (int mi = 0; mi < 4; ++mi)
        af[mi] = *(const bf16x8*)(bA + (wr * 128 + mh * 64 + mi * 16 + lr) * 64 +
                                  (((kh * 4 + kg) ^ l7) * 8));
      __builtin_amdgcn_s_barrier();
      __builtin_amdgcn_s_setprio(1);
#pragma unroll
      for (int mi = 0; mi < 4; ++mi)
#pragma unroll
        for (int ni = 0; ni < 4; ++ni)
          acc[mh * 4 + mi][ni] = __builtin_amdgcn_mfma_f32_16x16x32_bf16(
              bfr[kh][ni], af[mi], acc[mh * 4 + mi][ni], 0, 0, 0);
      __builtin_amdgcn_s_setprio(0);
      __builtin_amdgcn_s_barrier();
    }
  }

  __syncthreads();
  if (bn >= 2048) {
#pragma unroll
    for (int mi = 0; mi < 8; ++mi)
#pragma unroll
      for (int ni = 0; ni < 4; ++ni) {
        int r = bm + wr * 128 + mi * 16 + lr;
        int c = bn + wc * 64 + ni * 16 + kg * 4 - 2048;
        int bh2 = (r >> 11) * 16 + (c >> 6);
        int j = r & 2047;
        u16* vrow = VT + ((size_t)bh2 * 64 + (c & 63)) * 2048 + j;
        f32x4 a = acc[mi][ni];
#pragma unroll
        for (int rr = 0; rr < 4; ++rr) vrow[(size_t)rr * 2048] = f2h(a[rr]);
      }
  } else {
    float scale = (bn < 1024) ? EKF : 1.0f;
#pragma unroll
    for (int mi = 0; mi < 8; ++mi)
#pragma unroll
      for (int ni = 0; ni < 4; ++ni) {
        int row = wr * 128 + mi * 16 + lr;
        u32 off = (u32)row * 256 + wc * 64 + (((ni * 4 + kg) ^ (lr & 6)) * 4);
        f32x4 a = acc[mi][ni];
        *(uint2*)((u16*)smem + off) =
            make_uint2(pack2(a[0] * scale, a[1] * scale), pack2(a[2] * scale, a[3] * scale));
      }
    __syncthreads();
#pragma unroll
    for (int i = 0; i < 16; ++i) {
      int row = i * 16 + (tid >> 5);
      int lc = tid & 31;
      int blk = lc >> 3, cc = lc & 7;
      uint4 v = *(const uint4*)((const u16*)smem + (u32)row * 256 + blk * 64 +
                                (((2 * cc) ^ (row & 6)) * 4));
      *(uint4*)(QK + (size_t)(bm + row) * 2048 + bn + blk * 64 + cc * 8) = v;
    }
  }
}

// ---------------- out-proj GEMM (unchanged from R5) ----------------
__global__ __launch_bounds__(256, 2) void gemm_out_kernel(const u16* __restrict__ A,
                                                          const u16* __restrict__ BT,
                                                          float* __restrict__ C) {
  __shared__ __attribute__((aligned(16))) u16 smem[2][12288];  // A 64x64 + B 128x64 per buf
  const int tid = threadIdx.x;
  const int wave = tid >> 6;
  const int lane = tid & 63;
  const int lr = lane & 15;
  const int kg = lane >> 4;
  const int lr7 = lr & 7;
  const int wm = (wave >> 1) * 32;  // M half (32 rows per wave)
  const int wn = (wave & 1) * 64;   // N half (64 cols per wave)

  const int b = blockIdx.x;
  const int xcd = b & 7, loc = b >> 3;           // loc 0..63
  const int bm = (xcd * 8 + (loc >> 3)) * 64;    // 64 M-panels, 8 per XCD
  const int bn = (loc & 7) * 128;                // 8 N-tiles

  const int sr = tid >> 3;                        // 0..31
  const int scg = ((tid & 7) ^ (sr & 7)) * 8;     // swizzled source col (u16)
  const u16* pa = A + (size_t)(bm + sr) * 1024 + scg;
  const u16* pb = BT + (size_t)(bn + sr) * 1024 + scg;
  const u32 lw = (u32)wave * 512;

  f32x4 acc[2][4];
#pragma unroll
  for (int i = 0; i < 2; ++i)
#pragma unroll
    for (int j = 0; j < 4; ++j) {
      f32x4 z = {0.f, 0.f, 0.f, 0.f};
      acc[i][j] = z;
    }

  {  // prologue: stage tile 0 into buffer 0
    u16* dA = smem[0];
    u16* dB = smem[0] + 4096;
#pragma unroll
    for (int i = 0; i < 2; ++i) gld_lds16(pa + (size_t)(i * 32) * 1024, dA + lw + i * 2048);
#pragma unroll
    for (int i = 0; i < 4; ++i) gld_lds16(pb + (size_t)(i * 32) * 1024, dB + lw + i * 2048);
  }

  for (int t = 0; t < 16; ++t) {
    __syncthreads();  // tile t's loads complete
    const u16* bA = smem[t & 1];
    const u16* bB = bA + 4096;
    if (t + 1 < 16) {  // issue next tile with a full compute-phase of lead
      u16* dA = smem[(t + 1) & 1];
      u16* dB = dA + 4096;
      const int k1 = (t + 1) * 64;
#pragma unroll
      for (int i = 0; i < 2; ++i) gld_lds16(pa + (size_t)(i * 32) * 1024 + k1, dA + lw + i * 2048);
#pragma unroll
      for (int i = 0; i < 4; ++i) gld_lds16(pb + (size_t)(i * 32) * 1024 + k1, dB + lw + i * 2048);
    }
#pragma unroll
    for (int kk = 0; kk < 2; ++kk) {
      const int ch = ((kk * 4 + kg) ^ lr7) * 8;
      bf16x8 af[2], bfr[4];
#pragma unroll
      for (int mi = 0; mi < 2; ++mi)
        af[mi] = *(const bf16x8*)(bA + (wm + mi * 16 + lr) * 64 + ch);
#pragma unroll
      for (int ni = 0; ni < 4; ++ni)
        bfr[ni] = *(const bf16x8*)(bB + (wn + ni * 16 + lr) * 64 + ch);
      __builtin_amdgcn_s_setprio(1);
#pragma unroll
      for (int mi = 0; mi < 2; ++mi)
#pragma unroll
        for (int ni = 0; ni < 4; ++ni)
          acc[mi][ni] = __builtin_amdgcn_mfma_f32_16x16x32_bf16(bfr[ni], af[mi], acc[mi][ni], 0, 0, 0);
      __builtin_amdgcn_s_setprio(0);
    }
  }

  // epilogue: stage fp32 [64][64] col-halves through LDS, coalesced float4 out
  float* buf = (float*)smem;
#pragma unroll
  for (int hc = 0; hc < 2; ++hc) {
    __syncthreads();
    if ((wave & 1) == hc) {
#pragma unroll
      for (int mi = 0; mi < 2; ++mi)
#pragma unroll
        for (int ni = 0; ni < 4; ++ni) {
          int row = wm + mi * 16 + lr;                 // 0..63 (two waves cover all)
          int cp = ((ni * 4 + kg) ^ lr) * 4;           // 16-chunk swizzle, key lr
          *(f32x4*)(buf + row * 64 + cp) = acc[mi][ni];
        }
    }
    __syncthreads();
#pragma unroll
    for (int i = 0; i < 4; ++i) {
      int row = i * 16 + (tid >> 4);
      int lc = tid & 15;
      float4 v = *(const float4*)(buf + row * 64 + ((lc ^ (row & 15)) * 4));
      *(float4*)(C + (size_t)(bm + row) * 1024 + bn + hc * 64 + lc * 4) = v;
    }
  }
}

// ---------------- MFMA flash attention v11: in-register P + balanced qi ----------
// Changes vs R5:
//  (1) Window-balanced qi map: qi = (g&1) ? g>>1 : 31-(g>>1), g=idx>>5. Every 256-block
//      dispatch window averages 16.5 rounds/block -> per-CU makespan ~66 rounds flat
//      (was 52..80 with heavy-first).
//  (2) P->PV redistribution fully in registers via permlane32_swap + permlane16_swap
//      (fixed permutation over lane bits 4-5; derivation lane-verified). Removes the
//      sP LDS round-trip (4 ds_write + 2 ds_read_b128 + fence + lgkm wait per
//      wave-round) and frees 8KB LDS -> 32KB/block -> 5 blocks/CU.
__global__ __launch_bounds__(256, 4) void attn_mfma_kernel(const u16* __restrict__ qk,
                                                           const u16* __restrict__ vt,
                                                           u16* __restrict__ out) {
  __shared__ __attribute__((aligned(16))) u16 sK[2][64 * 64];  // [j][d] swizzled
  __shared__ __attribute__((aligned(16))) u16 sV[2][64 * 64];  // [d][j] swizzled

  const int tid = threadIdx.x;
  const int wave = tid >> 6;
  const int lane = tid & 63;
  const int lr = lane & 15;  // q col (B), j/d row (A)
  const int kg = lane >> 4;  // k-group / row-quad
  const int l7 = lr & 7;

  int idx = blockIdx.x;
  int g = idx >> 5;
  int qi = (g & 1) ? (g >> 1) : (31 - (g >> 1));  // balanced heavy/light interleave
  int bh = idx & 31;
  int b = bh >> 4, h = bh & 15;
  int q0 = qi * 64;

  const u16* qbase = qk + (size_t)b * 2048 * 2048 + h * 64;
  const u16* kbase = qbase + 1024;
  const u16* vbase = vt + (size_t)bh * 64 * 2048;
  u16* obase = out + (size_t)b * 2048 * 1024 + h * 64;

  const int sra = wave * 16 + (lane >> 3);
  const int srb = sra + 8;
  const int sc = lane & 7;
  const u32 koffA = (u32)sra * 2048 + (u32)((sc ^ (sra & 7)) * 8);
  const u32 koffB = (u32)srb * 2048 + (u32)((sc ^ (srb & 7)) * 8);
  const u32 ldsA = (wave * 2 + 0) * 512;
  const u32 ldsB = (wave * 2 + 1) * 512;

  const int qcol = q0 + wave * 16 + lr;
  bf16x8 qf0, qf1;
  {
    const u16* qrow = qbase + (size_t)qcol * 2048;
    qf0 = *(const bf16x8*)(qrow + kg * 8);
    qf1 = *(const bf16x8*)(qrow + 32 + kg * 8);
  }

  const u32 ka0 = (u32)(lr * 64 + ((kg ^ l7) * 8));
  const u32 ka1 = (u32)(lr * 64 + (((4 + kg) ^ l7) * 8));

  f32x4 oacc[4];
#pragma unroll
  for (int i = 0; i < 4; ++i) {
    f32x4 z = {0.f, 0.f, 0.f, 0.f};
    oacc[i] = z;
  }
  float lsum = 0.f;

  const int nrounds = qi + 1;
  gld_lds16(kbase + koffA, sK[0] + ldsA);
  gld_lds16(kbase + koffB, sK[0] + ldsB);
  gld_lds16(vbase + koffA, sV[0] + ldsA);
  gld_lds16(vbase + koffB, sV[0] + ldsB);
  __syncthreads();

  for (int t = 0; t < nrounds; ++t) {
    if (t + 1 < nrounds) {
      int j1 = (t + 1) * 64;
      u16* dK = sK[(t + 1) & 1];
      u16* dV = sV[(t + 1) & 1];
      gld_lds16(kbase + (size_t)j1 * 2048 + koffA, dK + ldsA);
      gld_lds16(kbase + (size_t)j1 * 2048 + koffB, dK + ldsB);
      gld_lds16(vbase + j1 + koffA, dV + ldsA);
      gld_lds16(vbase + j1 + koffB, dV + ldsB);
    }
    const u16* sKb = sK[t & 1];
    const u16* sVb = sV[t & 1];
    const bool diag = (t == qi);

    // QK^T + exp2; P kept in registers: wA[m][jt] = pk(p[2m], p[2m+1]) covers
    // j2 = 8*jt + 2*kg + m (j2 = j/2).
    u32 wA0[4], wA1[4];
#pragma unroll
    for (int jt = 0; jt < 4; ++jt) {
      if (!diag || jt <= wave) {
        bf16x8 kf0 = *(const bf16x8*)(sKb + jt * 1024 + ka0);
        bf16x8 kf1 = *(const bf16x8*)(sKb + jt * 1024 + ka1);
        f32x4 c = {0.f, 0.f, 0.f, 0.f};
        c = __builtin_amdgcn_mfma_f32_16x16x32_bf16(kf0, qf0, c, 0, 0, 0);
        c = __builtin_amdgcn_mfma_f32_16x16x32_bf16(kf1, qf1, c, 0, 0, 0);
        float p0 = exp2f(c[0]);
        float p1 = exp2f(c[1]);
        float p2 = exp2f(c[2]);
        float p3 = exp2f(c[3]);
        if (diag && jt == wave) {
          int jr = kg * 4;
          p0 = (jr + 0 <= lr) ? p0 : 0.f;
          p1 = (jr + 1 <= lr) ? p1 : 0.f;
          p2 = (jr + 2 <= lr) ? p2 : 0.f;
          p3 = (jr + 3 <= lr) ? p3 : 0.f;
        }
        lsum += (p0 + p1) + (p2 + p3);
        wA0[jt] = pkf16(p0, p1);
        wA1[jt] = pkf16(p2, p3);
      } else {
        wA0[jt] = 0u;
        wA1[jt] = 0u;
      }
    }

    // In-register redistribution (lane bits 4-5 permutation):
    // pair (jt, jt+1) m-words -> pf words via permlane32_swap then permlane16_swap.
    // After both swaps: x holds j2 = base + 4*kg, y holds j2 = base + 4*kg + 2.
    u32 x0 = wA0[0], y0 = wA0[1];
    asm volatile("v_permlane32_swap_b32 %0, %1" : "+v"(x0), "+v"(y0));
    asm volatile("v_permlane16_swap_b32 %0, %1" : "+v"(x0), "+v"(y0));
    u32 x1 = wA1[0], y1 = wA1[1];
    asm volatile("v_permlane32_swap_b32 %0, %1" : "+v"(x1), "+v"(y1));
    asm volatile("v_permlane16_swap_b32 %0, %1" : "+v"(x1), "+v"(y1));
    u32 x2 = wA0[2], y2 = wA0[3];
    asm volatile("v_permlane32_swap_b32 %0, %1" : "+v"(x2), "+v"(y2));
    asm volatile("v_permlane16_swap_b32 %0, %1" : "+v"(x2), "+v"(y2));
    u32 x3 = wA1[2], y3 = wA1[3];
    asm volatile("v_permlane32_swap_b32 %0, %1" : "+v"(x3), "+v"(y3));
    asm volatile("v_permlane16_swap_b32 %0, %1" : "+v"(x3), "+v"(y3));
    u32x4 pw0 = {x0, x1, y0, y1};  // P[q][j = 8kg .. 8kg+7]
    u32x4 pw1 = {x2, x3, y2, y3};  // P[q][j = 32+8kg .. 32+8kg+7]
    f16x8 pf0 = __builtin_bit_cast(f16x8, pw0);
    f16x8 pf1 = __builtin_bit_cast(f16x8, pw1);

    __builtin_amdgcn_s_setprio(1);
#pragma unroll
    for (int dt = 0; dt < 4; ++dt) {
      f16x8 vf0 = *(const f16x8*)(sVb + dt * 1024 + ka0);
      f16x8 vf1 = *(const f16x8*)(sVb + dt * 1024 + ka1);
      oacc[dt] = __builtin_amdgcn_mfma_f32_16x16x32_f16(vf0, pf0, oacc[dt], 0, 0, 0);
      oacc[dt] = __builtin_amdgcn_mfma_f32_16x16x32_f16(vf1, pf1, oacc[dt], 0, 0, 0);
    }
    __builtin_amdgcn_s_setprio(0);
    __syncthreads();
  }

  lsum += __shfl_xor(lsum, 16);
  lsum += __shfl_xor(lsum, 32);
  float inv = 1.0f / lsum;

  u16* orow = obase + (size_t)qcol * 1024;
#pragma unroll
  for (int dt = 0; dt < 4; ++dt) {
    uint2 o2 = make_uint2(pack2(oacc[dt][0] * inv, oacc[dt][1] * inv),
                          pack2(oacc[dt][2] * inv, oacc[dt][3] * inv));
    *(uint2*)(orow + dt * 16 + kg * 4) = o2;
  }
}

// ---------------- launch ----------------
extern "C" void kernel_launch(void* const* d_in, const int* in_sizes, int n_in,
                              void* d_out, int out_size, void* d_ws, size_t ws_size,
                              hipStream_t stream) {
  const float* x = (const float*)d_in[0];      // [2,2048,1024]
  const float* w_qkv = (const float*)d_in[1];  // [1024,3072]
  const float* w_out = (const float*)d_in[2];  // [1024,1024]
  float* out = (float*)d_out;                  // [2,2048,1024] fp32

  char* ws = (char*)d_ws;
  u16* xb    = (u16*)(ws);                //  8 MB: x bf16 [4096,1024]
  u16* wqkvT = (u16*)(ws + (8u << 20));   //  6 MB: w_qkv^T bf16 [3072,1024]
  u16* woutT = (u16*)(ws + (14u << 20));  //  2 MB: w_out^T bf16 [1024,1024]
  u16* qkb   = (u16*)(ws + (16u << 20));  // 16 MB: q|k bf16 [4096,2048]
  u16* vtb   = (u16*)(ws + (32u << 20));  //  8 MB: V^T f16 [32,64,2048]
  u16* attn  = (u16*)(ws + (40u << 20));  //  8 MB: attn out bf16 [4096,1024]

  prepass_kernel<<<5120, 256, 0, stream>>>(x, w_qkv, w_out, xb, wqkvT, woutT);

  gemm_qkv256_kernel<<<192, 512, 0, stream>>>(xb, wqkvT, qkb, vtb);

  attn_mfma_kernel<<<1024, 256, 0, stream>>>(qkb, vtb, attn);

  gemm_out_kernel<<<512, 256, 0, stream>>>(attn, woutT, out);
}

// Round 7
// 168.377 us; speedup vs baseline: 1.0232x; 1.0232x over previous
//
#include <hip/hip_runtime.h>

typedef unsigned short u16;
typedef unsigned int u32;

typedef __bf16 bf16x8 __attribute__((ext_vector_type(8)));
typedef _Float16 f16x8 __attribute__((ext_vector_type(8)));
typedef float f32x4 __attribute__((ext_vector_type(4)));
typedef u32 u32x4 __attribute__((ext_vector_type(4)));

typedef __attribute__((address_space(1))) u32 as1_u32;
typedef __attribute__((address_space(3))) u32 as3_u32;

#define EKF 0.18033688011112042f  // 0.125 * log2(e), folded into Q at GEMM1

__device__ __forceinline__ u16 f2bf(float x) {
  u32 u = __float_as_uint(x);
  u = u + 0x7fffu + ((u >> 16) & 1u);   // RNE
  return (u16)(u >> 16);
}
__device__ __forceinline__ u32 pack2(float a, float b) {
  return (u32)f2bf(a) | ((u32)f2bf(b) << 16);
}
__device__ __forceinline__ u32 pkf16(float a, float b) {
  return __builtin_bit_cast(u32, __builtin_amdgcn_cvt_pkrtz(a, b));
}
__device__ __forceinline__ u16 f2h(float a) {
  return (u16)(pkf16(a, a) & 0xffffu);
}
__device__ __forceinline__ void gld_lds16(const u16* g, const u16* l) {
  __builtin_amdgcn_global_load_lds((const as1_u32*)g, (as3_u32*)l, 16, 0, 0);
}

// ---------------- fused prepass: x cast + both weight transposes ----------------
__global__ __launch_bounds__(256) void prepass_kernel(const float* __restrict__ x,
                                                      const float* __restrict__ w_qkv,
                                                      const float* __restrict__ w_out,
                                                      u16* __restrict__ xb,
                                                      u16* __restrict__ wqkvT,
                                                      u16* __restrict__ woutT) {
  __shared__ float tile[64][65];
  int bid = blockIdx.x;
  int t = threadIdx.x;
  if (bid < 4096) {
    int i = bid * 256 + t;
    float4 v = ((const float4*)x)[i];
    uint2 r;
    r.x = pack2(v.x, v.y);
    r.y = pack2(v.z, v.w);
    ((uint2*)xb)[i] = r;
    return;
  }
  const float* W;
  u16* WT;
  int K, N, bx, by;
  if (bid < 4096 + 768) {
    int b2 = bid - 4096;
    W = w_qkv; WT = wqkvT; K = 1024; N = 3072; bx = b2 & 15; by = b2 >> 4;
  } else {
    int b2 = bid - 4864;
    W = w_out; WT = woutT; K = 1024; N = 1024; bx = b2 & 15; by = b2 >> 4;
  }
  int k0 = bx * 64, n0 = by * 64;
  int r = t >> 4, c4 = (t & 15) * 4;
#pragma unroll
  for (int i = 0; i < 4; ++i) {
    int row = r + i * 16;
    float4 v = *(const float4*)&W[(size_t)(k0 + row) * N + n0 + c4];
    tile[row][c4 + 0] = v.x; tile[row][c4 + 1] = v.y;
    tile[row][c4 + 2] = v.z; tile[row][c4 + 3] = v.w;
  }
  __syncthreads();
#pragma unroll
  for (int i = 0; i < 4; ++i) {
    int n = r + i * 16;
    uint2 o;
    o.x = pack2(tile[c4 + 0][n], tile[c4 + 1][n]);
    o.y = pack2(tile[c4 + 2][n], tile[c4 + 3][n]);
    *(uint2*)&WT[(size_t)(n0 + n) * K + k0 + c4] = o;
  }
}

// ---------------- 256x256 8-phase QKV GEMM (unchanged) ----------------
__global__ __launch_bounds__(512, 2) void gemm_qkv256_kernel(const u16* __restrict__ A,
                                                             const u16* __restrict__ BT,
                                                             u16* __restrict__ QK,
                                                             u16* __restrict__ VT) {
  __shared__ __attribute__((aligned(16))) u16 smem[65536];  // 128 KiB -> 1 block/CU
  const int tid = threadIdx.x;
  const int wave = tid >> 6;
  const int lane = tid & 63;
  const int lr = lane & 15;
  const int kg = lane >> 4;
  const int l7 = lr & 7;
  const int wr = wave >> 2;   // 0..1 : M half
  const int wc = wave & 3;    // 0..3 : N quarter

  int b = blockIdx.x;
  int sw = (b & 7) * 24 + (b >> 3);
  const int bn = (sw % 12) * 256;
  const int bm = (sw / 12) * 256;

  const int srow = tid >> 3;
  const int scg = ((tid & 7) ^ (srow & 7)) * 8;  // swizzled source col (u16)
  const u16* pa = A + (size_t)(bm + srow) * 1024 + scg;
  const u16* pb = BT + (size_t)(bn + srow) * 1024 + scg;
  const u32 lw = (u32)wave * 512;

  f32x4 acc[8][4];
#pragma unroll
  for (int i = 0; i < 8; ++i)
#pragma unroll
    for (int j = 0; j < 4; ++j) {
      f32x4 z = {0.f, 0.f, 0.f, 0.f};
      acc[i][j] = z;
    }

  {
    u16* dA = (u16*)smem;
    u16* dB = (u16*)smem + 16384;
#pragma unroll
    for (int i = 0; i < 4; ++i) gld_lds16(pa + (size_t)(i * 64) * 1024, dA + lw + i * 4096);
#pragma unroll
    for (int i = 0; i < 4; ++i) gld_lds16(pb + (size_t)(i * 64) * 1024, dB + lw + i * 4096);
  }

  for (int t = 0; t < 16; ++t) {
    __syncthreads();
    const u16* bA = smem + (t & 1) * 32768;
    const u16* bB = bA + 16384;
    if (t + 1 < 16) {
      u16* dA = (u16*)smem + ((t + 1) & 1) * 32768;
      u16* dB = dA + 16384;
      const int k1 = (t + 1) * 64;
#pragma unroll
      for (int i = 0; i < 4; ++i) gld_lds16(pa + (size_t)(i * 64) * 1024 + k1, dA + lw + i * 4096);
#pragma unroll
      for (int i = 0; i < 4; ++i) gld_lds16(pb + (size_t)(i * 64) * 1024 + k1, dB + lw + i * 4096);
    }
    bf16x8 bfr[2][4];
#pragma unroll
    for (int kh = 0; kh < 2; ++kh)
#pragma unroll
      for (int ni = 0; ni < 4; ++ni)
        bfr[kh][ni] = *(const bf16x8*)(bB + (wc * 64 + ni * 16 + lr) * 64 +
                                       (((kh * 4 + kg) ^ l7) * 8));
#pragma unroll
    for (int ph = 0; ph < 4; ++ph) {
      const int mh = ph >> 1, kh = ph & 1;
      bf16x8 af[4];
#pragma unroll
      for (int mi = 0; mi < 4; ++mi)
        af[mi] = *(const bf16x8*)(bA + (wr * 128 + mh * 64 + mi * 16 + lr) * 64 +
                                  (((kh * 4 + kg) ^ l7) * 8));
      __builtin_amdgcn_s_barrier();
      __builtin_amdgcn_s_setprio(1);
#pragma unroll
      for (int mi = 0; mi < 4; ++mi)
#pragma unroll
        for (int ni = 0; ni < 4; ++ni)
          acc[mh * 4 + mi][ni] = __builtin_amdgcn_mfma_f32_16x16x32_bf16(
              bfr[kh][ni], af[mi], acc[mh * 4 + mi][ni], 0, 0, 0);
      __builtin_amdgcn_s_setprio(0);
      __builtin_amdgcn_s_barrier();
    }
  }

  __syncthreads();
  if (bn >= 2048) {
#pragma unroll
    for (int mi = 0; mi < 8; ++mi)
#pragma unroll
      for (int ni = 0; ni < 4; ++ni) {
        int r = bm + wr * 128 + mi * 16 + lr;
        int c = bn + wc * 64 + ni * 16 + kg * 4 - 2048;
        int bh2 = (r >> 11) * 16 + (c >> 6);
        int j = r & 2047;
        u16* vrow = VT + ((size_t)bh2 * 64 + (c & 63)) * 2048 + j;
        f32x4 a = acc[mi][ni];
#pragma unroll
        for (int rr = 0; rr < 4; ++rr) vrow[(size_t)rr * 2048] = f2h(a[rr]);
      }
  } else {
    float scale = (bn < 1024) ? EKF : 1.0f;
#pragma unroll
    for (int mi = 0; mi < 8; ++mi)
#pragma unroll
      for (int ni = 0; ni < 4; ++ni) {
        int row = wr * 128 + mi * 16 + lr;
        u32 off = (u32)row * 256 + wc * 64 + (((ni * 4 + kg) ^ (lr & 6)) * 4);
        f32x4 a = acc[mi][ni];
        *(uint2*)((u16*)smem + off) =
            make_uint2(pack2(a[0] * scale, a[1] * scale), pack2(a[2] * scale, a[3] * scale));
      }
    __syncthreads();
#pragma unroll
    for (int i = 0; i < 16; ++i) {
      int row = i * 16 + (tid >> 5);
      int lc = tid & 31;
      int blk = lc >> 3, cc = lc & 7;
      uint4 v = *(const uint4*)((const u16*)smem + (u32)row * 256 + blk * 64 +
                                (((2 * cc) ^ (row & 6)) * 4));
      *(uint4*)(QK + (size_t)(bm + row) * 2048 + bn + blk * 64 + cc * 8) = v;
    }
  }
}

// ---------------- out-proj GEMM (unchanged from R5) ----------------
__global__ __launch_bounds__(256, 2) void gemm_out_kernel(const u16* __restrict__ A,
                                                          const u16* __restrict__ BT,
                                                          float* __restrict__ C) {
  __shared__ __attribute__((aligned(16))) u16 smem[2][12288];  // A 64x64 + B 128x64 per buf
  const int tid = threadIdx.x;
  const int wave = tid >> 6;
  const int lane = tid & 63;
  const int lr = lane & 15;
  const int kg = lane >> 4;
  const int lr7 = lr & 7;
  const int wm = (wave >> 1) * 32;  // M half (32 rows per wave)
  const int wn = (wave & 1) * 64;   // N half (64 cols per wave)

  const int b = blockIdx.x;
  const int xcd = b & 7, loc = b >> 3;           // loc 0..63
  const int bm = (xcd * 8 + (loc >> 3)) * 64;    // 64 M-panels, 8 per XCD
  const int bn = (loc & 7) * 128;                // 8 N-tiles

  const int sr = tid >> 3;                        // 0..31
  const int scg = ((tid & 7) ^ (sr & 7)) * 8;     // swizzled source col (u16)
  const u16* pa = A + (size_t)(bm + sr) * 1024 + scg;
  const u16* pb = BT + (size_t)(bn + sr) * 1024 + scg;
  const u32 lw = (u32)wave * 512;

  f32x4 acc[2][4];
#pragma unroll
  for (int i = 0; i < 2; ++i)
#pragma unroll
    for (int j = 0; j < 4; ++j) {
      f32x4 z = {0.f, 0.f, 0.f, 0.f};
      acc[i][j] = z;
    }

  {  // prologue: stage tile 0 into buffer 0
    u16* dA = smem[0];
    u16* dB = smem[0] + 4096;
#pragma unroll
    for (int i = 0; i < 2; ++i) gld_lds16(pa + (size_t)(i * 32) * 1024, dA + lw + i * 2048);
#pragma unroll
    for (int i = 0; i < 4; ++i) gld_lds16(pb + (size_t)(i * 32) * 1024, dB + lw + i * 2048);
  }

  for (int t = 0; t < 16; ++t) {
    __syncthreads();  // tile t's loads complete
    const u16* bA = smem[t & 1];
    const u16* bB = bA + 4096;
    if (t + 1 < 16) {  // issue next tile with a full compute-phase of lead
      u16* dA = smem[(t + 1) & 1];
      u16* dB = dA + 4096;
      const int k1 = (t + 1) * 64;
#pragma unroll
      for (int i = 0; i < 2; ++i) gld_lds16(pa + (size_t)(i * 32) * 1024 + k1, dA + lw + i * 2048);
#pragma unroll
      for (int i = 0; i < 4; ++i) gld_lds16(pb + (size_t)(i * 32) * 1024 + k1, dB + lw + i * 2048);
    }
#pragma unroll
    for (int kk = 0; kk < 2; ++kk) {
      const int ch = ((kk * 4 + kg) ^ lr7) * 8;
      bf16x8 af[2], bfr[4];
#pragma unroll
      for (int mi = 0; mi < 2; ++mi)
        af[mi] = *(const bf16x8*)(bA + (wm + mi * 16 + lr) * 64 + ch);
#pragma unroll
      for (int ni = 0; ni < 4; ++ni)
        bfr[ni] = *(const bf16x8*)(bB + (wn + ni * 16 + lr) * 64 + ch);
      __builtin_amdgcn_s_setprio(1);
#pragma unroll
      for (int mi = 0; mi < 2; ++mi)
#pragma unroll
        for (int ni = 0; ni < 4; ++ni)
          acc[mi][ni] = __builtin_amdgcn_mfma_f32_16x16x32_bf16(bfr[ni], af[mi], acc[mi][ni], 0, 0, 0);
      __builtin_amdgcn_s_setprio(0);
    }
  }

  // epilogue: stage fp32 [64][64] col-halves through LDS, coalesced float4 out
  float* buf = (float*)smem;
#pragma unroll
  for (int hc = 0; hc < 2; ++hc) {
    __syncthreads();
    if ((wave & 1) == hc) {
#pragma unroll
      for (int mi = 0; mi < 2; ++mi)
#pragma unroll
        for (int ni = 0; ni < 4; ++ni) {
          int row = wm + mi * 16 + lr;                 // 0..63 (two waves cover all)
          int cp = ((ni * 4 + kg) ^ lr) * 4;           // 16-chunk swizzle, key lr
          *(f32x4*)(buf + row * 64 + cp) = acc[mi][ni];
        }
    }
    __syncthreads();
#pragma unroll
    for (int i = 0; i < 4; ++i) {
      int row = i * 16 + (tid >> 4);
      int lc = tid & 15;
      float4 v = *(const float4*)(buf + row * 64 + ((lc ^ (row & 15)) * 4));
      *(float4*)(C + (size_t)(bm + row) * 1024 + bn + hc * 64 + lc * 4) = v;
    }
  }
}

// ---------------- MFMA flash attention v12: in-register P + stride-256-balanced map ----
// Block->(qi,bh) map: idx = k*256 + c, k in [0,4), w = c>>4.
//   qi = {w, 31-w, 15-w, 16+w}[k],  bh = (c&15) | ((k&2)<<3)
// Bijective over qi x bh (each (qi,bh) pair exactly once). For EVERY c, the four
// co-resident blocks {c, c+256, c+512, c+768} have qi sum = 62 -> exactly 66
// rounds/CU (R6's map had parity-correlated sums 30..104 -> the regression).
// In-register P via permlane32+16 swaps (R6, verified): bank conflicts = 0, sP freed.
__global__ __launch_bounds__(256, 4) void attn_mfma_kernel(const u16* __restrict__ qk,
                                                           const u16* __restrict__ vt,
                                                           u16* __restrict__ out) {
  __shared__ __attribute__((aligned(16))) u16 sK[2][64 * 64];  // [j][d] swizzled
  __shared__ __attribute__((aligned(16))) u16 sV[2][64 * 64];  // [d][j] swizzled

  const int tid = threadIdx.x;
  const int wave = tid >> 6;
  const int lane = tid & 63;
  const int lr = lane & 15;  // q col (B), j/d row (A)
  const int kg = lane >> 4;  // k-group / row-quad
  const int l7 = lr & 7;

  const int idx = blockIdx.x;
  const int k = idx >> 8;
  const int c = idx & 255;
  const int w = c >> 4;
  const int qi = (k == 0) ? w : (k == 1) ? (31 - w) : (k == 2) ? (15 - w) : (16 + w);
  const int bh = (c & 15) | ((k & 2) << 3);
  const int b = bh >> 4, h = bh & 15;
  const int q0 = qi * 64;

  const u16* qbase = qk + (size_t)b * 2048 * 2048 + h * 64;
  const u16* kbase = qbase + 1024;
  const u16* vbase = vt + (size_t)bh * 64 * 2048;
  u16* obase = out + (size_t)b * 2048 * 1024 + h * 64;

  const int sra = wave * 16 + (lane >> 3);
  const int srb = sra + 8;
  const int sc = lane & 7;
  const u32 koffA = (u32)sra * 2048 + (u32)((sc ^ (sra & 7)) * 8);
  const u32 koffB = (u32)srb * 2048 + (u32)((sc ^ (srb & 7)) * 8);
  const u32 ldsA = (wave * 2 + 0) * 512;
  const u32 ldsB = (wave * 2 + 1) * 512;

  const int qcol = q0 + wave * 16 + lr;
  bf16x8 qf0, qf1;
  {
    const u16* qrow = qbase + (size_t)qcol * 2048;
    qf0 = *(const bf16x8*)(qrow + kg * 8);
    qf1 = *(const bf16x8*)(qrow + 32 + kg * 8);
  }

  const u32 ka0 = (u32)(lr * 64 + ((kg ^ l7) * 8));
  const u32 ka1 = (u32)(lr * 64 + (((4 + kg) ^ l7) * 8));

  f32x4 oacc[4];
#pragma unroll
  for (int i = 0; i < 4; ++i) {
    f32x4 z = {0.f, 0.f, 0.f, 0.f};
    oacc[i] = z;
  }
  float lsum = 0.f;

  const int nrounds = qi + 1;
  gld_lds16(kbase + koffA, sK[0] + ldsA);
  gld_lds16(kbase + koffB, sK[0] + ldsB);
  gld_lds16(vbase + koffA, sV[0] + ldsA);
  gld_lds16(vbase + koffB, sV[0] + ldsB);
  __syncthreads();

  for (int t = 0; t < nrounds; ++t) {
    if (t + 1 < nrounds) {
      int j1 = (t + 1) * 64;
      u16* dK = sK[(t + 1) & 1];
      u16* dV = sV[(t + 1) & 1];
      gld_lds16(kbase + (size_t)j1 * 2048 + koffA, dK + ldsA);
      gld_lds16(kbase + (size_t)j1 * 2048 + koffB, dK + ldsB);
      gld_lds16(vbase + j1 + koffA, dV + ldsA);
      gld_lds16(vbase + j1 + koffB, dV + ldsB);
    }
    const u16* sKb = sK[t & 1];
    const u16* sVb = sV[t & 1];
    const bool diag = (t == qi);

    // QK^T + exp2; P kept in registers: wA[m][jt] = pk(p[2m], p[2m+1]) covers
    // j2 = 8*jt + 2*kg + m (j2 = j/2).
    u32 wA0[4], wA1[4];
#pragma unroll
    for (int jt = 0; jt < 4; ++jt) {
      if (!diag || jt <= wave) {
        bf16x8 kf0 = *(const bf16x8*)(sKb + jt * 1024 + ka0);
        bf16x8 kf1 = *(const bf16x8*)(sKb + jt * 1024 + ka1);
        f32x4 cc = {0.f, 0.f, 0.f, 0.f};
        cc = __builtin_amdgcn_mfma_f32_16x16x32_bf16(kf0, qf0, cc, 0, 0, 0);
        cc = __builtin_amdgcn_mfma_f32_16x16x32_bf16(kf1, qf1, cc, 0, 0, 0);
        float p0 = exp2f(cc[0]);
        float p1 = exp2f(cc[1]);
        float p2 = exp2f(cc[2]);
        float p3 = exp2f(cc[3]);
        if (diag && jt == wave) {
          int jr = kg * 4;
          p0 = (jr + 0 <= lr) ? p0 : 0.f;
          p1 = (jr + 1 <= lr) ? p1 : 0.f;
          p2 = (jr + 2 <= lr) ? p2 : 0.f;
          p3 = (jr + 3 <= lr) ? p3 : 0.f;
        }
        lsum += (p0 + p1) + (p2 + p3);
        wA0[jt] = pkf16(p0, p1);
        wA1[jt] = pkf16(p2, p3);
      } else {
        wA0[jt] = 0u;
        wA1[jt] = 0u;
      }
    }

    // In-register redistribution (lane bits 4-5 permutation):
    u32 x0 = wA0[0], y0 = wA0[1];
    asm volatile("v_permlane32_swap_b32 %0, %1" : "+v"(x0), "+v"(y0));
    asm volatile("v_permlane16_swap_b32 %0, %1" : "+v"(x0), "+v"(y0));
    u32 x1 = wA1[0], y1 = wA1[1];
    asm volatile("v_permlane32_swap_b32 %0, %1" : "+v"(x1), "+v"(y1));
    asm volatile("v_permlane16_swap_b32 %0, %1" : "+v"(x1), "+v"(y1));
    u32 x2 = wA0[2], y2 = wA0[3];
    asm volatile("v_permlane32_swap_b32 %0, %1" : "+v"(x2), "+v"(y2));
    asm volatile("v_permlane16_swap_b32 %0, %1" : "+v"(x2), "+v"(y2));
    u32 x3 = wA1[2], y3 = wA1[3];
    asm volatile("v_permlane32_swap_b32 %0, %1" : "+v"(x3), "+v"(y3));
    asm volatile("v_permlane16_swap_b32 %0, %1" : "+v"(x3), "+v"(y3));
    u32x4 pw0 = {x0, x1, y0, y1};  // P[q][j = 8kg .. 8kg+7]
    u32x4 pw1 = {x2, x3, y2, y3};  // P[q][j = 32+8kg .. 32+8kg+7]
    f16x8 pf0 = __builtin_bit_cast(f16x8, pw0);
    f16x8 pf1 = __builtin_bit_cast(f16x8, pw1);

    __builtin_amdgcn_s_setprio(1);
#pragma unroll
    for (int dt = 0; dt < 4; ++dt) {
      f16x8 vf0 = *(const f16x8*)(sVb + dt * 1024 + ka0);
      f16x8 vf1 = *(const f16x8*)(sVb + dt * 1024 + ka1);
      oacc[dt] = __builtin_amdgcn_mfma_f32_16x16x32_f16(vf0, pf0, oacc[dt], 0, 0, 0);
      oacc[dt] = __builtin_amdgcn_mfma_f32_16x16x32_f16(vf1, pf1, oacc[dt], 0, 0, 0);
    }
    __builtin_amdgcn_s_setprio(0);
    __syncthreads();
  }

  lsum += __shfl_xor(lsum, 16);
  lsum += __shfl_xor(lsum, 32);
  float inv = 1.0f / lsum;

  u16* orow = obase + (size_t)qcol * 1024;
#pragma unroll
  for (int dt = 0; dt < 4; ++dt) {
    uint2 o2 = make_uint2(pack2(oacc[dt][0] * inv, oacc[dt][1] * inv),
                          pack2(oacc[dt][2] * inv, oacc[dt][3] * inv));
    *(uint2*)(orow + dt * 16 + kg * 4) = o2;
  }
}

// ---------------- launch ----------------
extern "C" void kernel_launch(void* const* d_in, const int* in_sizes, int n_in,
                              void* d_out, int out_size, void* d_ws, size_t ws_size,
                              hipStream_t stream) {
  const float* x = (const float*)d_in[0];      // [2,2048,1024]
  const float* w_qkv = (const float*)d_in[1];  // [1024,3072]
  const float* w_out = (const float*)d_in[2];  // [1024,1024]
  float* out = (float*)d_out;                  // [2,2048,1024] fp32

  char* ws = (char*)d_ws;
  u16* xb    = (u16*)(ws);                //  8 MB: x bf16 [4096,1024]
  u16* wqkvT = (u16*)(ws + (8u << 20));   //  6 MB: w_qkv^T bf16 [3072,1024]
  u16* woutT = (u16*)(ws + (14u << 20));  //  2 MB: w_out^T bf16 [1024,1024]
  u16* qkb   = (u16*)(ws + (16u << 20));  // 16 MB: q|k bf16 [4096,2048]
  u16* vtb   = (u16*)(ws + (32u << 20));  //  8 MB: V^T f16 [32,64,2048]
  u16* attn  = (u16*)(ws + (40u << 20));  //  8 MB: attn out bf16 [4096,1024]

  prepass_kernel<<<5120, 256, 0, stream>>>(x, w_qkv, w_out, xb, wqkvT, woutT);

  gemm_qkv256_kernel<<<192, 512, 0, stream>>>(xb, wqkvT, qkb, vtb);

  attn_mfma_kernel<<<1024, 256, 0, stream>>>(qkb, vtb, attn);

  gemm_out_kernel<<<512, 256, 0, stream>>>(attn, woutT, out);
}

// Round 8
// 163.133 us; speedup vs baseline: 1.0561x; 1.0321x over previous
//
#include <hip/hip_runtime.h>

typedef unsigned short u16;
typedef unsigned int u32;

typedef __bf16 bf16x8 __attribute__((ext_vector_type(8)));
typedef _Float16 f16x8 __attribute__((ext_vector_type(8)));
typedef float f32x4 __attribute__((ext_vector_type(4)));

typedef __attribute__((address_space(1))) u32 as1_u32;
typedef __attribute__((address_space(3))) u32 as3_u32;

#define EKF 0.18033688011112042f  // 0.125 * log2(e), folded into Q at GEMM1

__device__ __forceinline__ u16 f2bf(float x) {
  u32 u = __float_as_uint(x);
  u = u + 0x7fffu + ((u >> 16) & 1u);   // RNE
  return (u16)(u >> 16);
}
__device__ __forceinline__ u32 pack2(float a, float b) {
  return (u32)f2bf(a) | ((u32)f2bf(b) << 16);
}
__device__ __forceinline__ u32 pkf16(float a, float b) {
  return __builtin_bit_cast(u32, __builtin_amdgcn_cvt_pkrtz(a, b));
}
__device__ __forceinline__ u16 f2h(float a) {
  return (u16)(pkf16(a, a) & 0xffffu);
}
__device__ __forceinline__ void gld_lds16(const u16* g, const u16* l) {
  __builtin_amdgcn_global_load_lds((const as1_u32*)g, (as3_u32*)l, 16, 0, 0);
}

// ---------------- fused prepass: x cast + both weight transposes ----------------
__global__ __launch_bounds__(256) void prepass_kernel(const float* __restrict__ x,
                                                      const float* __restrict__ w_qkv,
                                                      const float* __restrict__ w_out,
                                                      u16* __restrict__ xb,
                                                      u16* __restrict__ wqkvT,
                                                      u16* __restrict__ woutT) {
  __shared__ float tile[64][65];
  int bid = blockIdx.x;
  int t = threadIdx.x;
  if (bid < 4096) {
    int i = bid * 256 + t;
    float4 v = ((const float4*)x)[i];
    uint2 r;
    r.x = pack2(v.x, v.y);
    r.y = pack2(v.z, v.w);
    ((uint2*)xb)[i] = r;
    return;
  }
  const float* W;
  u16* WT;
  int K, N, bx, by;
  if (bid < 4096 + 768) {
    int b2 = bid - 4096;
    W = w_qkv; WT = wqkvT; K = 1024; N = 3072; bx = b2 & 15; by = b2 >> 4;
  } else {
    int b2 = bid - 4864;
    W = w_out; WT = woutT; K = 1024; N = 1024; bx = b2 & 15; by = b2 >> 4;
  }
  int k0 = bx * 64, n0 = by * 64;
  int r = t >> 4, c4 = (t & 15) * 4;
#pragma unroll
  for (int i = 0; i < 4; ++i) {
    int row = r + i * 16;
    float4 v = *(const float4*)&W[(size_t)(k0 + row) * N + n0 + c4];
    tile[row][c4 + 0] = v.x; tile[row][c4 + 1] = v.y;
    tile[row][c4 + 2] = v.z; tile[row][c4 + 3] = v.w;
  }
  __syncthreads();
#pragma unroll
  for (int i = 0; i < 4; ++i) {
    int n = r + i * 16;
    uint2 o;
    o.x = pack2(tile[c4 + 0][n], tile[c4 + 1][n]);
    o.y = pack2(tile[c4 + 2][n], tile[c4 + 3][n]);
    *(uint2*)&WT[(size_t)(n0 + n) * K + k0 + c4] = o;
  }
}

// ---------------- 256x256 8-phase QKV GEMM (unchanged) ----------------
__global__ __launch_bounds__(512, 2) void gemm_qkv256_kernel(const u16* __restrict__ A,
                                                             const u16* __restrict__ BT,
                                                             u16* __restrict__ QK,
                                                             u16* __restrict__ VT) {
  __shared__ __attribute__((aligned(16))) u16 smem[65536];  // 128 KiB -> 1 block/CU
  const int tid = threadIdx.x;
  const int wave = tid >> 6;
  const int lane = tid & 63;
  const int lr = lane & 15;
  const int kg = lane >> 4;
  const int l7 = lr & 7;
  const int wr = wave >> 2;   // 0..1 : M half
  const int wc = wave & 3;    // 0..3 : N quarter

  int b = blockIdx.x;
  int sw = (b & 7) * 24 + (b >> 3);
  const int bn = (sw % 12) * 256;
  const int bm = (sw / 12) * 256;

  const int srow = tid >> 3;
  const int scg = ((tid & 7) ^ (srow & 7)) * 8;  // swizzled source col (u16)
  const u16* pa = A + (size_t)(bm + srow) * 1024 + scg;
  const u16* pb = BT + (size_t)(bn + srow) * 1024 + scg;
  const u32 lw = (u32)wave * 512;

  f32x4 acc[8][4];
#pragma unroll
  for (int i = 0; i < 8; ++i)
#pragma unroll
    for (int j = 0; j < 4; ++j) {
      f32x4 z = {0.f, 0.f, 0.f, 0.f};
      acc[i][j] = z;
    }

  {
    u16* dA = (u16*)smem;
    u16* dB = (u16*)smem + 16384;
#pragma unroll
    for (int i = 0; i < 4; ++i) gld_lds16(pa + (size_t)(i * 64) * 1024, dA + lw + i * 4096);
#pragma unroll
    for (int i = 0; i < 4; ++i) gld_lds16(pb + (size_t)(i * 64) * 1024, dB + lw + i * 4096);
  }

  for (int t = 0; t < 16; ++t) {
    __syncthreads();
    const u16* bA = smem + (t & 1) * 32768;
    const u16* bB = bA + 16384;
    if (t + 1 < 16) {
      u16* dA = (u16*)smem + ((t + 1) & 1) * 32768;
      u16* dB = dA + 16384;
      const int k1 = (t + 1) * 64;
#pragma unroll
      for (int i = 0; i < 4; ++i) gld_lds16(pa + (size_t)(i * 64) * 1024 + k1, dA + lw + i * 4096);
#pragma unroll
      for (int i = 0; i < 4; ++i) gld_lds16(pb + (size_t)(i * 64) * 1024 + k1, dB + lw + i * 4096);
    }
    bf16x8 bfr[2][4];
#pragma unroll
    for (int kh = 0; kh < 2; ++kh)
#pragma unroll
      for (int ni = 0; ni < 4; ++ni)
        bfr[kh][ni] = *(const bf16x8*)(bB + (wc * 64 + ni * 16 + lr) * 64 +
                                       (((kh * 4 + kg) ^ l7) * 8));
#pragma unroll
    for (int ph = 0; ph < 4; ++ph) {
      const int mh = ph >> 1, kh = ph & 1;
      bf16x8 af[4];
#pragma unroll
      for (int mi = 0; mi < 4; ++mi)
        af[mi] = *(const bf16x8*)(bA + (wr * 128 + mh * 64 + mi * 16 + lr) * 64 +
                                  (((kh * 4 + kg) ^ l7) * 8));
      __builtin_amdgcn_s_barrier();
      __builtin_amdgcn_s_setprio(1);
#pragma unroll
      for (int mi = 0; mi < 4; ++mi)
#pragma unroll
        for (int ni = 0; ni < 4; ++ni)
          acc[mh * 4 + mi][ni] = __builtin_amdgcn_mfma_f32_16x16x32_bf16(
              bfr[kh][ni], af[mi], acc[mh * 4 + mi][ni], 0, 0, 0);
      __builtin_amdgcn_s_setprio(0);
      __builtin_amdgcn_s_barrier();
    }
  }

  __syncthreads();
  if (bn >= 2048) {
#pragma unroll
    for (int mi = 0; mi < 8; ++mi)
#pragma unroll
      for (int ni = 0; ni < 4; ++ni) {
        int r = bm + wr * 128 + mi * 16 + lr;
        int c = bn + wc * 64 + ni * 16 + kg * 4 - 2048;
        int bh2 = (r >> 11) * 16 + (c >> 6);
        int j = r & 2047;
        u16* vrow = VT + ((size_t)bh2 * 64 + (c & 63)) * 2048 + j;
        f32x4 a = acc[mi][ni];
#pragma unroll
        for (int rr = 0; rr < 4; ++rr) vrow[(size_t)rr * 2048] = f2h(a[rr]);
      }
  } else {
    float scale = (bn < 1024) ? EKF : 1.0f;
#pragma unroll
    for (int mi = 0; mi < 8; ++mi)
#pragma unroll
      for (int ni = 0; ni < 4; ++ni) {
        int row = wr * 128 + mi * 16 + lr;
        u32 off = (u32)row * 256 + wc * 64 + (((ni * 4 + kg) ^ (lr & 6)) * 4);
        f32x4 a = acc[mi][ni];
        *(uint2*)((u16*)smem + off) =
            make_uint2(pack2(a[0] * scale, a[1] * scale), pack2(a[2] * scale, a[3] * scale));
      }
    __syncthreads();
#pragma unroll
    for (int i = 0; i < 16; ++i) {
      int row = i * 16 + (tid >> 5);
      int lc = tid & 31;
      int blk = lc >> 3, cc = lc & 7;
      uint4 v = *(const uint4*)((const u16*)smem + (u32)row * 256 + blk * 64 +
                                (((2 * cc) ^ (row & 6)) * 4));
      *(uint4*)(QK + (size_t)(bm + row) * 2048 + bn + blk * 64 + cc * 8) = v;
    }
  }
}

// ---------------- out-proj GEMM (unchanged from R5) ----------------
__global__ __launch_bounds__(256, 2) void gemm_out_kernel(const u16* __restrict__ A,
                                                          const u16* __restrict__ BT,
                                                          float* __restrict__ C) {
  __shared__ __attribute__((aligned(16))) u16 smem[2][12288];  // A 64x64 + B 128x64 per buf
  const int tid = threadIdx.x;
  const int wave = tid >> 6;
  const int lane = tid & 63;
  const int lr = lane & 15;
  const int kg = lane >> 4;
  const int lr7 = lr & 7;
  const int wm = (wave >> 1) * 32;  // M half (32 rows per wave)
  const int wn = (wave & 1) * 64;   // N half (64 cols per wave)

  const int b = blockIdx.x;
  const int xcd = b & 7, loc = b >> 3;           // loc 0..63
  const int bm = (xcd * 8 + (loc >> 3)) * 64;    // 64 M-panels, 8 per XCD
  const int bn = (loc & 7) * 128;                // 8 N-tiles

  const int sr = tid >> 3;                        // 0..31
  const int scg = ((tid & 7) ^ (sr & 7)) * 8;     // swizzled source col (u16)
  const u16* pa = A + (size_t)(bm + sr) * 1024 + scg;
  const u16* pb = BT + (size_t)(bn + sr) * 1024 + scg;
  const u32 lw = (u32)wave * 512;

  f32x4 acc[2][4];
#pragma unroll
  for (int i = 0; i < 2; ++i)
#pragma unroll
    for (int j = 0; j < 4; ++j) {
      f32x4 z = {0.f, 0.f, 0.f, 0.f};
      acc[i][j] = z;
    }

  {  // prologue: stage tile 0 into buffer 0
    u16* dA = smem[0];
    u16* dB = smem[0] + 4096;
#pragma unroll
    for (int i = 0; i < 2; ++i) gld_lds16(pa + (size_t)(i * 32) * 1024, dA + lw + i * 2048);
#pragma unroll
    for (int i = 0; i < 4; ++i) gld_lds16(pb + (size_t)(i * 32) * 1024, dB + lw + i * 2048);
  }

  for (int t = 0; t < 16; ++t) {
    __syncthreads();  // tile t's loads complete
    const u16* bA = smem[t & 1];
    const u16* bB = bA + 4096;
    if (t + 1 < 16) {  // issue next tile with a full compute-phase of lead
      u16* dA = smem[(t + 1) & 1];
      u16* dB = dA + 4096;
      const int k1 = (t + 1) * 64;
#pragma unroll
      for (int i = 0; i < 2; ++i) gld_lds16(pa + (size_t)(i * 32) * 1024 + k1, dA + lw + i * 2048);
#pragma unroll
      for (int i = 0; i < 4; ++i) gld_lds16(pb + (size_t)(i * 32) * 1024 + k1, dB + lw + i * 2048);
    }
#pragma unroll
    for (int kk = 0; kk < 2; ++kk) {
      const int ch = ((kk * 4 + kg) ^ lr7) * 8;
      bf16x8 af[2], bfr[4];
#pragma unroll
      for (int mi = 0; mi < 2; ++mi)
        af[mi] = *(const bf16x8*)(bA + (wm + mi * 16 + lr) * 64 + ch);
#pragma unroll
      for (int ni = 0; ni < 4; ++ni)
        bfr[ni] = *(const bf16x8*)(bB + (wn + ni * 16 + lr) * 64 + ch);
      __builtin_amdgcn_s_setprio(1);
#pragma unroll
      for (int mi = 0; mi < 2; ++mi)
#pragma unroll
        for (int ni = 0; ni < 4; ++ni)
          acc[mi][ni] = __builtin_amdgcn_mfma_f32_16x16x32_bf16(bfr[ni], af[mi], acc[mi][ni], 0, 0, 0);
      __builtin_amdgcn_s_setprio(0);
    }
  }

  // epilogue: stage fp32 [64][64] col-halves through LDS, coalesced float4 out
  float* buf = (float*)smem;
#pragma unroll
  for (int hc = 0; hc < 2; ++hc) {
    __syncthreads();
    if ((wave & 1) == hc) {
#pragma unroll
      for (int mi = 0; mi < 2; ++mi)
#pragma unroll
        for (int ni = 0; ni < 4; ++ni) {
          int row = wm + mi * 16 + lr;                 // 0..63 (two waves cover all)
          int cp = ((ni * 4 + kg) ^ lr) * 4;           // 16-chunk swizzle, key lr
          *(f32x4*)(buf + row * 64 + cp) = acc[mi][ni];
        }
    }
    __syncthreads();
#pragma unroll
    for (int i = 0; i < 4; ++i) {
      int row = i * 16 + (tid >> 4);
      int lc = tid & 15;
      float4 v = *(const float4*)(buf + row * 64 + ((lc ^ (row & 15)) * 4));
      *(float4*)(C + (size_t)(bm + row) * 1024 + bn + hc * 64 + lc * 4) = v;
    }
  }
}

// ---------------- MFMA flash attention (R5 body) + XCD-aware bh placement -------
// R5's proven structure: LDS-staged P, heavy-first qi, setprio around PV.
// NEW: bh = (idx&7)*4 + ((idx>>3)&3) — consecutive blocks (-> consecutive XCDs
// under round-robin dispatch) share bh, so each XCD's L2 holds only 4 bh's of
// K/V (2 MB < 4 MB L2) -> K/V prefetch hits L2, shrinking the per-round vmcnt
// drain at the barrier. qi stays heavy-first in the major bits (bijective map).
__global__ __launch_bounds__(256, 4) void attn_mfma_kernel(const u16* __restrict__ qk,
                                                           const u16* __restrict__ vt,
                                                           u16* __restrict__ out) {
  __shared__ __attribute__((aligned(16))) u16 sK[2][64 * 64];  // [j][d] swizzled
  __shared__ __attribute__((aligned(16))) u16 sV[2][64 * 64];  // [d][j] swizzled
  __shared__ __attribute__((aligned(16))) u16 sP[4][16 * 64];  // [q][j] 8B-swizzled

  const int tid = threadIdx.x;
  const int wave = tid >> 6;
  const int lane = tid & 63;
  const int lr = lane & 15;  // q col (B), j/d row (A)
  const int kg = lane >> 4;  // k-group / row-quad
  const int l7 = lr & 7;

  int idx = blockIdx.x;
  int qi = 31 - (idx >> 5);                      // heavy q-tiles first
  int bh = (idx & 7) * 4 + ((idx >> 3) & 3);     // XCD-local bh grouping
  int b = bh >> 4, h = bh & 15;
  int q0 = qi * 64;

  const u16* qbase = qk + (size_t)b * 2048 * 2048 + h * 64;
  const u16* kbase = qbase + 1024;
  const u16* vbase = vt + (size_t)bh * 64 * 2048;
  u16* obase = out + (size_t)b * 2048 * 1024 + h * 64;

  const int sra = wave * 16 + (lane >> 3);
  const int srb = sra + 8;
  const int sc = lane & 7;
  const u32 koffA = (u32)sra * 2048 + (u32)((sc ^ (sra & 7)) * 8);
  const u32 koffB = (u32)srb * 2048 + (u32)((sc ^ (srb & 7)) * 8);
  const u32 ldsA = (wave * 2 + 0) * 512;
  const u32 ldsB = (wave * 2 + 1) * 512;

  const int qcol = q0 + wave * 16 + lr;
  bf16x8 qf0, qf1;
  {
    const u16* qrow = qbase + (size_t)qcol * 2048;
    qf0 = *(const bf16x8*)(qrow + kg * 8);
    qf1 = *(const bf16x8*)(qrow + 32 + kg * 8);
  }

  const u32 ka0 = (u32)(lr * 64 + ((kg ^ l7) * 8));
  const u32 ka1 = (u32)(lr * 64 + (((4 + kg) ^ l7) * 8));
  u16* const sPw = sP[wave];
  const u32 pr0 = (u32)(lr * 64 + (((kg * 2) ^ (l7 << 1)) * 4));
  const u32 pr1 = (u32)(lr * 64 + (((8 + kg * 2) ^ (l7 << 1)) * 4));

  f32x4 oacc[4];
#pragma unroll
  for (int i = 0; i < 4; ++i) {
    f32x4 z = {0.f, 0.f, 0.f, 0.f};
    oacc[i] = z;
  }
  float lsum = 0.f;

  const int nrounds = qi + 1;
  gld_lds16(kbase + koffA, sK[0] + ldsA);
  gld_lds16(kbase + koffB, sK[0] + ldsB);
  gld_lds16(vbase + koffA, sV[0] + ldsA);
  gld_lds16(vbase + koffB, sV[0] + ldsB);
  __syncthreads();

  for (int t = 0; t < nrounds; ++t) {
    if (t + 1 < nrounds) {
      int j1 = (t + 1) * 64;
      u16* dK = sK[(t + 1) & 1];
      u16* dV = sV[(t + 1) & 1];
      gld_lds16(kbase + (size_t)j1 * 2048 + koffA, dK + ldsA);
      gld_lds16(kbase + (size_t)j1 * 2048 + koffB, dK + ldsB);
      gld_lds16(vbase + j1 + koffA, dV + ldsA);
      gld_lds16(vbase + j1 + koffB, dV + ldsB);
    }
    const u16* sKb = sK[t & 1];
    const u16* sVb = sV[t & 1];
    const bool diag = (t == qi);

#pragma unroll
    for (int jt = 0; jt < 4; ++jt) {
      u16* pw = sPw + lr * 64 + (((jt * 4 + kg) ^ (l7 << 1)) * 4);
      if (!diag || jt <= wave) {
        bf16x8 kf0 = *(const bf16x8*)(sKb + jt * 1024 + ka0);
        bf16x8 kf1 = *(const bf16x8*)(sKb + jt * 1024 + ka1);
        f32x4 c = {0.f, 0.f, 0.f, 0.f};
        c = __builtin_amdgcn_mfma_f32_16x16x32_bf16(kf0, qf0, c, 0, 0, 0);
        c = __builtin_amdgcn_mfma_f32_16x16x32_bf16(kf1, qf1, c, 0, 0, 0);
        float p0 = exp2f(c[0]);
        float p1 = exp2f(c[1]);
        float p2 = exp2f(c[2]);
        float p3 = exp2f(c[3]);
        if (diag && jt == wave) {
          int jr = kg * 4;
          p0 = (jr + 0 <= lr) ? p0 : 0.f;
          p1 = (jr + 1 <= lr) ? p1 : 0.f;
          p2 = (jr + 2 <= lr) ? p2 : 0.f;
          p3 = (jr + 3 <= lr) ? p3 : 0.f;
        }
        lsum += (p0 + p1) + (p2 + p3);
        *(uint2*)pw = make_uint2(pkf16(p0, p1), pkf16(p2, p3));
      } else {
        *(uint2*)pw = make_uint2(0u, 0u);
      }
    }

    asm volatile("" ::: "memory");  // P writes precede P-frag reads (same wave)

    f16x8 pf0 = *(const f16x8*)(sPw + pr0);
    f16x8 pf1 = *(const f16x8*)(sPw + pr1);
    __builtin_amdgcn_s_setprio(1);
#pragma unroll
    for (int dt = 0; dt < 4; ++dt) {
      f16x8 vf0 = *(const f16x8*)(sVb + dt * 1024 + ka0);
      f16x8 vf1 = *(const f16x8*)(sVb + dt * 1024 + ka1);
      oacc[dt] = __builtin_amdgcn_mfma_f32_16x16x32_f16(vf0, pf0, oacc[dt], 0, 0, 0);
      oacc[dt] = __builtin_amdgcn_mfma_f32_16x16x32_f16(vf1, pf1, oacc[dt], 0, 0, 0);
    }
    __builtin_amdgcn_s_setprio(0);
    __syncthreads();
  }

  lsum += __shfl_xor(lsum, 16);
  lsum += __shfl_xor(lsum, 32);
  float inv = 1.0f / lsum;

  u16* orow = obase + (size_t)qcol * 1024;
#pragma unroll
  for (int dt = 0; dt < 4; ++dt) {
    uint2 o2 = make_uint2(pack2(oacc[dt][0] * inv, oacc[dt][1] * inv),
                          pack2(oacc[dt][2] * inv, oacc[dt][3] * inv));
    *(uint2*)(orow + dt * 16 + kg * 4) = o2;
  }
}

// ---------------- launch ----------------
extern "C" void kernel_launch(void* const* d_in, const int* in_sizes, int n_in,
                              void* d_out, int out_size, void* d_ws, size_t ws_size,
                              hipStream_t stream) {
  const float* x = (const float*)d_in[0];      // [2,2048,1024]
  const float* w_qkv = (const float*)d_in[1];  // [1024,3072]
  const float* w_out = (const float*)d_in[2];  // [1024,1024]
  float* out = (float*)d_out;                  // [2,2048,1024] fp32

  char* ws = (char*)d_ws;
  u16* xb    = (u16*)(ws);                //  8 MB: x bf16 [4096,1024]
  u16* wqkvT = (u16*)(ws + (8u << 20));   //  6 MB: w_qkv^T bf16 [3072,1024]
  u16* woutT = (u16*)(ws + (14u << 20));  //  2 MB: w_out^T bf16 [1024,1024]
  u16* qkb   = (u16*)(ws + (16u << 20));  // 16 MB: q|k bf16 [4096,2048]
  u16* vtb   = (u16*)(ws + (32u << 20));  //  8 MB: V^T f16 [32,64,2048]
  u16* attn  = (u16*)(ws + (40u << 20));  //  8 MB: attn out bf16 [4096,1024]

  prepass_kernel<<<5120, 256, 0, stream>>>(x, w_qkv, w_out, xb, wqkvT, woutT);

  gemm_qkv256_kernel<<<192, 512, 0, stream>>>(xb, wqkvT, qkb, vtb);

  attn_mfma_kernel<<<1024, 256, 0, stream>>>(qkb, vtb, attn);

  gemm_out_kernel<<<512, 256, 0, stream>>>(attn, woutT, out);
}